// Round 14
// baseline (71.136 us; speedup 1.0000x reference)
//
#include <hip/hip_runtime.h>
#include <hip/hip_fp16.h>
#include <math.h>

#define BATCH 2
#define RAYS  4096
#define NS    48
#define FEAT  32
#define HP    256
#define HID   64
#define NRAY  (BATCH*RAYS)
#define NSAMP (NRAY*NS)
#define S_DELTA (1.0f/47.0f)
#define PSZ   (HP*HP*FEAT)          // elements per plane
#define RPB   4                     // rays per (persistent) block

typedef unsigned short u16;
typedef __attribute__((ext_vector_type(8))) _Float16 half8;  // 8 f16 (4 VGPRs)
typedef __attribute__((ext_vector_type(4))) float facc4;     // 4 f32 accum

__device__ __forceinline__ float softplus_f(float t) {
    float e = __expf(-fabsf(t));
    return fmaxf(t, 0.0f) + __logf(1.0f + e);
}
__device__ __forceinline__ float sigmoid_f(float t) {
    return 1.0f / (1.0f + __expf(-t));
}

// ---- prep: planes f32 [bp][f][y][x] -> f16 [bp][y][x][f]; W1/3,W2 -> f16 B-frags
__global__ __launch_bounds__(256)
void prep_kernel(const float* __restrict__ planes,
                 const float* __restrict__ W1,
                 const float* __restrict__ W2,
                 u16* __restrict__ pT,
                 u16* __restrict__ W1F,
                 u16* __restrict__ W2F) {
    int idx = blockIdx.x * 256 + threadIdx.x;
    const int total = BATCH * 3 * HP * HP;
    if (idx < total) {
        int xy = idx % (HP * HP);
        int bp = idx / (HP * HP);
        const float* src = planes + (size_t)bp * FEAT * HP * HP + xy;
        unsigned o16[16];
        #pragma unroll
        for (int k = 0; k < 16; ++k) {
            unsigned lo = __half_as_ushort(__float2half_rn(src[(size_t)(2*k)   * HP*HP]));
            unsigned hi = __half_as_ushort(__float2half_rn(src[(size_t)(2*k+1) * HP*HP]));
            o16[k] = lo | (hi << 16);
        }
        uint4* dst = (uint4*)(pT + (size_t)idx * FEAT);
        #pragma unroll
        for (int q = 0; q < 4; ++q)
            dst[q] = make_uint4(o16[4*q], o16[4*q+1], o16[4*q+2], o16[4*q+3]);
    } else {
        int r = idx - total;              // 0..255 (one tail block)
        // W1F: B-frag of (W1/3)[32 k][64 n]; e=(nt*64+l)*8+i holds
        // f16(W1[k=(l>>4)*8+i][n=nt*16+(l&15)] / 3)
        #pragma unroll
        for (int i = 0; i < 8; ++i) {
            int e = r * 8 + i;            // 0..2047
            int nt = e >> 9, ll = (e >> 3) & 63, ii = e & 7;
            int k = ((ll >> 4) << 3) + ii;
            int nn = (nt << 4) + (ll & 15);
            W1F[e] = __half_as_ushort(__float2half_rn(W1[k * HID + nn] * (1.f/3.f)));
        }
        // W2F: B-frag of W2 padded [64 k][16 n]
        if (r < 128) {
            #pragma unroll
            for (int i = 0; i < 8; ++i) {
                int e = r * 8 + i;        // 0..1023
                int kk = e >> 9, ll = (e >> 3) & 63, ii = e & 7;
                int k = kk * 32 + ((ll >> 4) << 3) + ii;
                int nn = ll & 15;
                W2F[e] = (nn < 4) ? __half_as_ushort(__float2half_rn(W2[k * 4 + nn]))
                                  : (u16)0;
            }
        }
    }
}

// ---- compute 4 corner offsets (u16 elements from pbase) + weights ------
__device__ __forceinline__ void plane_addr(float gx, float gy, int fc8, unsigned pofs,
                                           unsigned* __restrict__ offs,
                                           float* __restrict__ wts) {
    float px = fmaf(gx, 127.5f, 127.5f);   // (gx+1)*0.5*(HP-1)
    float py = fmaf(gy, 127.5f, 127.5f);
    float fx = floorf(px), fy = floorf(py);
    float wx = px - fx, wy = py - fy;
    int x0 = (int)fx, y0 = (int)fy;
    int x1 = x0 + 1, y1 = y0 + 1;
    bool vx0 = (unsigned)x0 < HP, vx1 = (unsigned)x1 < HP;
    bool vy0 = (unsigned)y0 < HP, vy1 = (unsigned)y1 < HP;
    int cx0 = min(max(x0, 0), HP-1), cx1 = min(max(x1, 0), HP-1);
    int cy0 = min(max(y0, 0), HP-1), cy1 = min(max(y1, 0), HP-1);
    unsigned a00 = (unsigned)(cy0 * HP + cx0) * FEAT + fc8 + pofs;
    unsigned dxe = (unsigned)(cx1 - cx0) * FEAT;        // 0 or 32
    unsigned dye = (unsigned)(cy1 - cy0) * (HP * FEAT); // 0 or 8192
    offs[0] = a00;
    offs[1] = a00 + dxe;
    offs[2] = a00 + dye;
    offs[3] = a00 + dye + dxe;
    wts[0] = (vx0 && vy0) ? (1.f-wx)*(1.f-wy) : 0.f;
    wts[1] = (vx1 && vy0) ? wx*(1.f-wy)       : 0.f;
    wts[2] = (vx0 && vy1) ? (1.f-wx)*wy       : 0.f;
    wts[3] = (vx1 && vy1) ? wx*wy             : 0.f;
}

// ---- fused persistent: 4 rays/block, gather + f16 MFMA MLP + composite --
// block = 192 threads = 3 waves; per iteration: 48 samples = ONE ray.
// wave w: 16 samples; lane l: sample (l&15), feats (l>>4)*8..+7 == A-frag
// of mfma_f32_16x16x32_f16. C/D: row=4*(l>>4)+reg, col=l&15 (verified r7).
// Double-buffered s_smp so wave0's composite of ray i overlaps waves 1-2
// gathering ray i+1. Weights/bias hoisted out of the ray loop.
__global__ __launch_bounds__(192, 4)
void render_mfma(const u16* __restrict__ pT,
                 const float* __restrict__ rayo,
                 const float* __restrict__ rayd,
                 const float* __restrict__ jitter,
                 const u16* __restrict__ W1F,
                 const u16* __restrict__ W2F,
                 const float* __restrict__ b1,
                 const float* __restrict__ b2,
                 float* __restrict__ out) {
    __shared__ __align__(16) u16 hlds[3][1024];    // per-wave 16x64 f16, XOR-swizzled
    __shared__ __align__(16) float4 s_smp[2][48];  // double-buffered {dens,r,g,b}
    __shared__ float s_sd[2][48];

    const int t = threadIdx.x;
    const int w = t >> 6;
    const int l = t & 63;
    const int c = l & 15;          // A-row / C-col (sample-in-wave)
    const int g = l >> 4;          // k-chunk / C row-group
    const int R0 = blockIdx.x * RPB;
    const int ls = w * 16 + c;     // local sample == n
    const int b  = R0 >> 12;       // batch uniform across the block's rays
    const int fc8 = g * 8;
    const u16* pbase = pT + (size_t)b * 3 * PSZ;   // wave-uniform
    char* lb = (char*)&hlds[w][0];

    // hoisted loop-invariants: MLP weight fragments + biases
    uint4 B1q[4], B2q[2];
    #pragma unroll
    for (int nt = 0; nt < 4; ++nt)
        B1q[nt] = *(const uint4*)(W1F + (size_t)(nt * 64 + l) * 8);
    #pragma unroll
    for (int kk = 0; kk < 2; ++kk)
        B2q[kk] = *(const uint4*)(W2F + (size_t)(kk * 64 + l) * 8);
    float bb1[4];
    #pragma unroll
    for (int nt = 0; nt < 4; ++nt) bb1[nt] = b1[nt * 16 + c];
    const float bb2 = b2[c & 3];

    for (int it = 0; it < RPB; ++it) {
        const int ray = R0 + it;
        const int s   = ray * NS + ls;
        const int bi  = it & 1;

        const float jit = jitter[s];
        const float sd = fmaf((float)ls, S_DELTA, jit * S_DELTA);
        const float ox = rayo[ray*3+0], oy = rayo[ray*3+1], oz = rayo[ray*3+2];
        const float dx = rayd[ray*3+0], dy = rayd[ray*3+1], dz = rayd[ray*3+2];
        const float cxv = fmaf(sd, dx, ox);
        const float cyv = fmaf(sd, dy, oy);
        const float czv = fmaf(sd, dz, oz);

        // 12 corner offsets + weights
        unsigned offs[12];
        float wts[12];
        plane_addr(cxv, cyv, fc8, 0u,                offs + 0, wts + 0);  // (x,y)
        plane_addr(cxv, czv, fc8, (unsigned)PSZ,     offs + 4, wts + 4);  // (x,z)
        plane_addr(cyv, czv, fc8, (unsigned)(2*PSZ), offs + 8, wts + 8);  // (y,z)

        // gather + consume: 3 independent per-plane chains
        __half2 a0[4], a1[4], a2[4];
        #pragma unroll
        for (int i = 0; i < 4; ++i) {
            a0[i] = __float2half2_rn(0.f);
            a1[i] = __float2half2_rn(0.f);
            a2[i] = __float2half2_rn(0.f);
        }
        #pragma unroll
        for (int q = 0; q < 4; ++q) {
            union { uint4 u; __half2 h[4]; } d0, d1, d2;
            d0.u = *(const uint4*)(pbase + offs[q]);
            d1.u = *(const uint4*)(pbase + offs[4+q]);
            d2.u = *(const uint4*)(pbase + offs[8+q]);
            __half2 w0 = __float2half2_rn(wts[q]);
            __half2 w1 = __float2half2_rn(wts[4+q]);
            __half2 w2 = __float2half2_rn(wts[8+q]);
            #pragma unroll
            for (int j = 0; j < 4; ++j) {
                a0[j] = __hfma2(d0.h[j], w0, a0[j]);
                a1[j] = __hfma2(d1.h[j], w1, a1[j]);
                a2[j] = __hfma2(d2.h[j], w2, a2[j]);
            }
        }
        union { __half2 h[4]; half8 v; } A;
        #pragma unroll
        for (int i = 0; i < 4; ++i)
            A.h[i] = __hadd2(__hadd2(a0[i], a1[i]), a2[i]);

        // layer 1: H[16][64] = X @ (W1/3) + b1 (bias in C-init)
        facc4 H[4];
        #pragma unroll
        for (int nt = 0; nt < 4; ++nt) {
            facc4 Cb = {bb1[nt], bb1[nt], bb1[nt], bb1[nt]};
            union { uint4 q; half8 v; } B; B.q = B1q[nt];
            H[nt] = __builtin_amdgcn_mfma_f32_16x16x32_f16(A.v, B.v, Cb, 0, 0, 0);
        }

        // softplus -> f16 -> LDS (XOR swizzle: byte ^= (row&7)<<4)
        #pragma unroll
        for (int nt = 0; nt < 4; ++nt) {
            #pragma unroll
            for (int r = 0; r < 4; ++r) {
                const int row = g * 4 + r;                  // sample-in-wave
                const float hv = softplus_f(H[nt][r]);
                const int off = row * 128 + ((((nt * 16 + c) * 2)) ^ ((row & 7) << 4));
                *(u16*)(lb + off) = __half_as_ushort(__float2half_rn(hv));
            }
        }
        // wave-private LDS: in-order DS pipe + compiler lgkmcnt; no barrier.

        // layer 2: O[16][4] = softplus(H) @ W2 + b2 (bias in C-init)
        facc4 O = {bb2, bb2, bb2, bb2};
        #pragma unroll
        for (int kk = 0; kk < 2; ++kk) {
            union { uint4 q; half8 v; } A2;
            const int off = c * 128 + ((kk * 64 + g * 16) ^ ((c & 7) << 4));
            A2.q = *(const uint4*)(lb + off);
            union { uint4 q; half8 v; } B2; B2.q = B2q[kk];
            O = __builtin_amdgcn_mfma_f32_16x16x32_f16(A2.v, B2.v, O, 0, 0, 0);
        }

        // epilogue: lane holds O[sample 4g+r][col c]; cols 0..3 valid
        if (c < 4) {
            #pragma unroll
            for (int r = 0; r < 4; ++r) {
                const int li = w * 16 + g * 4 + r;
                const float o = O[r];
                const float val = (c == 0) ? softplus_f(o)
                                           : (sigmoid_f(o) * 1.002f - 0.001f);
                ((float*)&s_smp[bi][li])[c] = val;
            }
        }
        if (g == 0) s_sd[bi][ls] = sd;
        __syncthreads();
        // waves 1-2 proceed to next ray; wave 0 composites this one.

        if (w == 0) {
            const bool valid = l < NS;
            float4 v = make_float4(0.f, 0.f, 0.f, 0.f);
            float sdc = 0.f;
            if (valid) { v = s_smp[bi][l]; sdc = s_sd[bi][l]; }
            float sdn = __shfl_down(sdc, 1);

            float alpha = 0.f, lg = 0.f;
            if (valid) {
                float delta = (l < NS - 1) ? (sdn - sdc) : 1e10f;
                float tt = __expf(-delta * v.x);
                alpha = 1.0f - tt;
                lg = __logf(tt + 1e-10f);
            }
            float sacc = lg;
            #pragma unroll
            for (int off = 1; off < 64; off <<= 1) {
                float u = __shfl_up(sacc, off);
                if (l >= off) sacc += u;
            }
            float finalLog = __shfl(sacc, NS - 1);
            float T   = __expf(sacc - lg);
            float wgt = valid ? alpha * T : 0.f;

            float rf = wgt * v.y, gf = wgt * v.z, bf = wgt * v.w;
            float dep = wgt * sdc, wsum = wgt;
            #pragma unroll
            for (int off = 32; off; off >>= 1) {
                rf   += __shfl_xor(rf, off);
                gf   += __shfl_xor(gf, off);
                bf   += __shfl_xor(bf, off);
                dep  += __shfl_xor(dep, off);
                wsum += __shfl_xor(wsum, off);
            }
            if (l == 0) {
                out[ray * 3 + 0] = rf;
                out[ray * 3 + 1] = gf;
                out[ray * 3 + 2] = bf;
                out[NRAY * 3 + ray] = dep;
                out[NRAY * 4 + ray] = wsum;
                out[NRAY * 5 + ray] = __expf(finalLog);
            }
        }
    }
}

// ---- fallback: fully fused fp32, direct plane layout -------------------
__global__ __launch_bounds__(192)
void render_fused(const float* __restrict__ pl,
                  const float* __restrict__ rayo,
                  const float* __restrict__ rayd,
                  const float* __restrict__ jitter,
                  const float* __restrict__ W1, const float* __restrict__ b1,
                  const float* __restrict__ W2, const float* __restrict__ b2,
                  float* __restrict__ out) {
    __shared__ float4 smpb[192];
    __shared__ float  sdsb[192];
    int tid = threadIdx.x;
    int lr  = tid / NS;
    int n   = tid - lr * NS;
    int ray = blockIdx.x * 4 + lr;
    int b   = ray >> 12;

    float jit = jitter[ray * NS + n];
    float sd  = (float)n * S_DELTA + jit * S_DELTA;
    float ox = rayo[ray*3+0], oy = rayo[ray*3+1], oz = rayo[ray*3+2];
    float dx = rayd[ray*3+0], dy = rayd[ray*3+1], dz = rayd[ray*3+2];
    float cx = fmaf(sd, dx, ox), cy = fmaf(sd, dy, oy), cz = fmaf(sd, dz, oz);

    float xv[32];
    #pragma unroll
    for (int i = 0; i < 32; ++i) xv[i] = 0.f;
    const size_t psz = (size_t)HP * HP * FEAT;
    const float* base = pl + (size_t)b * 3 * psz;
    float gxs[3] = {cx, cx, cy}, gys[3] = {cy, cz, cz};
    for (int p = 0; p < 3; ++p) {
        float px = (gxs[p] + 1.0f) * 0.5f * (float)(HP - 1);
        float py = (gys[p] + 1.0f) * 0.5f * (float)(HP - 1);
        float fx = floorf(px), fy = floorf(py);
        float wx = px - fx, wy = py - fy;
        int x0 = (int)fx, y0 = (int)fy, x1 = x0 + 1, y1 = y0 + 1;
        const float* pb = base + p * psz;
        float ws[4] = {(1.f-wx)*(1.f-wy), wx*(1.f-wy), (1.f-wx)*wy, wx*wy};
        int xs[4] = {x0, x1, x0, x1}, ys[4] = {y0, y0, y1, y1};
        for (int q = 0; q < 4; ++q) {
            if ((unsigned)xs[q] < HP && (unsigned)ys[q] < HP) {
                const float* pp = pb + (size_t)ys[q] * HP + xs[q];
                #pragma unroll
                for (int f = 0; f < 32; ++f)
                    xv[f] = fmaf(ws[q], pp[(size_t)f * HP * HP], xv[f]);
            }
        }
    }
    #pragma unroll
    for (int i = 0; i < 32; ++i) xv[i] *= (1.f/3.f);

    float o0 = b2[0], o1 = b2[1], o2 = b2[2], o3 = b2[3];
    #pragma unroll
    for (int j = 0; j < HID; ++j) {
        float hj = b1[j];
        #pragma unroll
        for (int f = 0; f < FEAT; ++f) hj = fmaf(xv[f], W1[f * HID + j], hj);
        hj = softplus_f(hj);
        o0 = fmaf(hj, W2[j*4+0], o0);
        o1 = fmaf(hj, W2[j*4+1], o1);
        o2 = fmaf(hj, W2[j*4+2], o2);
        o3 = fmaf(hj, W2[j*4+3], o3);
    }
    smpb[tid] = make_float4(softplus_f(o0),
                            sigmoid_f(o1) * 1.002f - 0.001f,
                            sigmoid_f(o2) * 1.002f - 0.001f,
                            sigmoid_f(o3) * 1.002f - 0.001f);
    sdsb[tid] = sd;
    __syncthreads();

    if (tid < 4) {
        int rray = blockIdx.x * 4 + tid;
        const float4* sp  = &smpb[tid * NS];
        const float*  sdp = &sdsb[tid * NS];
        float T = 1.0f, rf = 0.f, gf = 0.f, bfv = 0.f, dep = 0.f, wsum = 0.f;
        for (int m = 0; m < NS; ++m) {
            float4 vv = sp[m];
            float sdc = sdp[m];
            float delta = (m < NS - 1) ? (sdp[m+1] - sdc) : 1e10f;
            float alpha = 1.0f - __expf(-delta * vv.x);
            float wq = alpha * T;
            rf = fmaf(wq, vv.y, rf);
            gf = fmaf(wq, vv.z, gf);
            bfv = fmaf(wq, vv.w, bfv);
            dep = fmaf(wq, sdc, dep);
            wsum += wq;
            T *= (1.0f - alpha + 1e-10f);
        }
        out[rray*3+0] = rf;
        out[rray*3+1] = gf;
        out[rray*3+2] = bfv;
        out[NRAY*3 + rray] = dep;
        out[NRAY*4 + rray] = wsum;
        out[NRAY*5 + rray] = T;
    }
}

extern "C" void kernel_launch(void* const* d_in, const int* in_sizes, int n_in,
                              void* d_out, int out_size, void* d_ws, size_t ws_size,
                              hipStream_t stream) {
    const float* planes = (const float*)d_in[0];
    const float* rayo   = (const float*)d_in[1];
    const float* rayd   = (const float*)d_in[2];
    const float* jitter = (const float*)d_in[3];
    const float* W1     = (const float*)d_in[4];
    const float* b1     = (const float*)d_in[5];
    const float* W2     = (const float*)d_in[6];
    const float* b2     = (const float*)d_in[7];
    float* out = (float*)d_out;

    const size_t pT_bytes = (size_t)BATCH * 3 * HP * HP * FEAT * 2;  // 25.2 MB f16
    const size_t w1f_off  = pT_bytes;
    const size_t w2f_off  = w1f_off + (size_t)FEAT * HID * 2;  // 4 KB
    const size_t need     = w2f_off + (size_t)HID * 16 * 2;    // +2 KB

    if (ws_size >= need) {
        char* ws = (char*)d_ws;
        u16* pT  = (u16*)ws;
        u16* W1F = (u16*)(ws + w1f_off);
        u16* W2F = (u16*)(ws + w2f_off);
        const int tgrid = BATCH * 3 * HP * HP / 256 + 1;
        hipLaunchKernelGGL(prep_kernel, dim3(tgrid), dim3(256), 0, stream,
                           planes, W1, W2, pT, W1F, W2F);
        hipLaunchKernelGGL(render_mfma, dim3(NRAY / RPB), dim3(192), 0, stream,
                           pT, rayo, rayd, jitter, W1F, W2F, b1, b2, out);
    } else {
        hipLaunchKernelGGL(render_fused, dim3(NRAY / 4), dim3(192), 0, stream,
                           planes, rayo, rayd, jitter, W1, b1, W2, b2, out);
    }
}

// Round 15
// 58.435 us; speedup vs baseline: 1.2174x; 1.2174x over previous
//
#include <hip/hip_runtime.h>
#include <hip/hip_fp16.h>
#include <math.h>

#define BATCH 2
#define RAYS  4096
#define NS    48
#define FEAT  32
#define HP    256
#define HID   64
#define NRAY  (BATCH*RAYS)
#define NSAMP (NRAY*NS)
#define S_DELTA (1.0f/47.0f)
#define PSZ   (HP*HP*FEAT)          // elements per plane

typedef unsigned short u16;
typedef __attribute__((ext_vector_type(8))) _Float16 half8;  // 8 f16 (4 VGPRs)
typedef __attribute__((ext_vector_type(4))) float facc4;     // 4 f32 accum
typedef __attribute__((ext_vector_type(4))) unsigned u32x4;  // asm-load payload

__device__ __forceinline__ float softplus_f(float t) {
    float e = __expf(-fabsf(t));
    return fmaxf(t, 0.0f) + __logf(1.0f + e);
}
__device__ __forceinline__ float sigmoid_f(float t) {
    return 1.0f / (1.0f + __expf(-t));
}

// ---- prep: planes f32 [bp][f][y][x] -> f16 [bp][y][x][f]; W1/3,W2 -> f16 B-frags
__global__ __launch_bounds__(256)
void prep_kernel(const float* __restrict__ planes,
                 const float* __restrict__ W1,
                 const float* __restrict__ W2,
                 u16* __restrict__ pT,
                 u16* __restrict__ W1F,
                 u16* __restrict__ W2F) {
    int idx = blockIdx.x * 256 + threadIdx.x;
    const int total = BATCH * 3 * HP * HP;
    if (idx < total) {
        int xy = idx % (HP * HP);
        int bp = idx / (HP * HP);
        const float* src = planes + (size_t)bp * FEAT * HP * HP + xy;
        unsigned o16[16];
        #pragma unroll
        for (int k = 0; k < 16; ++k) {
            unsigned lo = __half_as_ushort(__float2half_rn(src[(size_t)(2*k)   * HP*HP]));
            unsigned hi = __half_as_ushort(__float2half_rn(src[(size_t)(2*k+1) * HP*HP]));
            o16[k] = lo | (hi << 16);
        }
        uint4* dst = (uint4*)(pT + (size_t)idx * FEAT);
        #pragma unroll
        for (int q = 0; q < 4; ++q)
            dst[q] = make_uint4(o16[4*q], o16[4*q+1], o16[4*q+2], o16[4*q+3]);
    } else {
        int r = idx - total;              // 0..255 (one tail block)
        // W1F: B-frag of (W1/3)[32 k][64 n]; e=(nt*64+l)*8+i holds
        // f16(W1[k=(l>>4)*8+i][n=nt*16+(l&15)] / 3)
        #pragma unroll
        for (int i = 0; i < 8; ++i) {
            int e = r * 8 + i;            // 0..2047
            int nt = e >> 9, ll = (e >> 3) & 63, ii = e & 7;
            int k = ((ll >> 4) << 3) + ii;
            int nn = (nt << 4) + (ll & 15);
            W1F[e] = __half_as_ushort(__float2half_rn(W1[k * HID + nn] * (1.f/3.f)));
        }
        // W2F: B-frag of W2 padded [64 k][16 n]
        if (r < 128) {
            #pragma unroll
            for (int i = 0; i < 8; ++i) {
                int e = r * 8 + i;        // 0..1023
                int kk = e >> 9, ll = (e >> 3) & 63, ii = e & 7;
                int k = kk * 32 + ((ll >> 4) << 3) + ii;
                int nn = ll & 15;
                W2F[e] = (nn < 4) ? __half_as_ushort(__float2half_rn(W2[k * 4 + nn]))
                                  : (u16)0;
            }
        }
    }
}

// ---- compute 4 corner offsets (u16 elements from pbase) + weights ------
__device__ __forceinline__ void plane_addr(float gx, float gy, int fc8, unsigned pofs,
                                           unsigned* __restrict__ offs,
                                           float* __restrict__ wts) {
    float px = fmaf(gx, 127.5f, 127.5f);   // (gx+1)*0.5*(HP-1)
    float py = fmaf(gy, 127.5f, 127.5f);
    float fx = floorf(px), fy = floorf(py);
    float wx = px - fx, wy = py - fy;
    int x0 = (int)fx, y0 = (int)fy;
    int x1 = x0 + 1, y1 = y0 + 1;
    bool vx0 = (unsigned)x0 < HP, vx1 = (unsigned)x1 < HP;
    bool vy0 = (unsigned)y0 < HP, vy1 = (unsigned)y1 < HP;
    int cx0 = min(max(x0, 0), HP-1), cx1 = min(max(x1, 0), HP-1);
    int cy0 = min(max(y0, 0), HP-1), cy1 = min(max(y1, 0), HP-1);
    unsigned a00 = (unsigned)(cy0 * HP + cx0) * FEAT + fc8 + pofs;
    unsigned dxe = (unsigned)(cx1 - cx0) * FEAT;        // 0 or 32
    unsigned dye = (unsigned)(cy1 - cy0) * (HP * FEAT); // 0 or 8192
    offs[0] = a00;
    offs[1] = a00 + dxe;
    offs[2] = a00 + dye;
    offs[3] = a00 + dye + dxe;
    wts[0] = (vx0 && vy0) ? (1.f-wx)*(1.f-wy) : 0.f;
    wts[1] = (vx1 && vy0) ? wx*(1.f-wy)       : 0.f;
    wts[2] = (vx0 && vy1) ? (1.f-wx)*wy       : 0.f;
    wts[3] = (vx1 && vy1) ? wx*wy             : 0.f;
}

// ---- fused: gather + f16 MFMA MLP + in-block composite -----------------
// block = 192 threads = 3 waves = 48 samples = EXACTLY ONE RAY.
// wave w: 16 samples; lane l: sample (l&15), feats (l>>4)*8..+7 == A-frag
// of mfma_f32_16x16x32_f16. C/D: row=4*(l>>4)+reg, col=l&15 (verified r7).
// The 12 corner loads are issued via inline asm so the compiler cannot
// serialize them into load->consume batches (r10/r11 showed it pins VGPR=32
// and eats full L2/L3 latency ~3x per sample otherwise).
__global__ __launch_bounds__(192, 4)
void render_mfma(const u16* __restrict__ pT,
                 const float* __restrict__ rayo,
                 const float* __restrict__ rayd,
                 const float* __restrict__ jitter,
                 const u16* __restrict__ W1F,
                 const u16* __restrict__ W2F,
                 const float* __restrict__ b1,
                 const float* __restrict__ b2,
                 float* __restrict__ out) {
    __shared__ __align__(16) u16 hlds[3][1024];  // per-wave 16x64 f16, XOR-swizzled
    __shared__ __align__(16) float4 s_smp[48];   // {dens,r,g,b} per sample
    __shared__ float s_sd[48];

    const int t = threadIdx.x;
    const int w = t >> 6;
    const int l = t & 63;
    const int c = l & 15;          // A-row / C-col (sample-in-wave)
    const int g = l >> 4;          // k-chunk / C row-group
    const int ray = blockIdx.x;    // one ray per block
    const int ls = w * 16 + c;     // local sample == n
    const int s  = ray * NS + ls;  // global sample
    const int b  = ray >> 12;

    const float jit = jitter[s];
    const float sd = fmaf((float)ls, S_DELTA, jit * S_DELTA);
    const float ox = rayo[ray*3+0], oy = rayo[ray*3+1], oz = rayo[ray*3+2];
    const float dx = rayd[ray*3+0], dy = rayd[ray*3+1], dz = rayd[ray*3+2];
    const float cxv = fmaf(sd, dx, ox);
    const float cyv = fmaf(sd, dy, oy);
    const float czv = fmaf(sd, dz, oz);

    // phase A: all 12 corner offsets + weights
    const int fc8 = g * 8;
    unsigned offs[12];
    float wts[12];
    plane_addr(cxv, cyv, fc8, 0u,                offs + 0, wts + 0);  // (x,y)
    plane_addr(cxv, czv, fc8, (unsigned)PSZ,     offs + 4, wts + 4);  // (x,z)
    plane_addr(cyv, czv, fc8, (unsigned)(2*PSZ), offs + 8, wts + 8);  // (y,z)

    // phase B: force-issue ALL 12 loads back-to-back via inline asm
    const u16* pbase = pT + (size_t)b * 3 * PSZ;   // wave-uniform
    u32x4 dat[12];
    #pragma unroll
    for (int i = 0; i < 12; ++i) {
        const u16* ap = pbase + offs[i];
        asm volatile("global_load_dwordx4 %0, %1, off"
                     : "=v"(dat[i]) : "v"(ap));
    }
    asm volatile("s_waitcnt vmcnt(0)" ::: "memory");
    __builtin_amdgcn_sched_barrier(0);   // rule #18: block VALU hoisting past wait

    // phase C: consume — 3 independent per-plane chains (ILP)
    __half2 a0[4], a1[4], a2[4];
    #pragma unroll
    for (int i = 0; i < 4; ++i) {
        a0[i] = __float2half2_rn(0.f);
        a1[i] = __float2half2_rn(0.f);
        a2[i] = __float2half2_rn(0.f);
    }
    #pragma unroll
    for (int q = 0; q < 4; ++q) {
        union { u32x4 u; __half2 h[4]; } d0, d1, d2;
        d0.u = dat[q]; d1.u = dat[4+q]; d2.u = dat[8+q];
        __half2 w0 = __float2half2_rn(wts[q]);
        __half2 w1 = __float2half2_rn(wts[4+q]);
        __half2 w2 = __float2half2_rn(wts[8+q]);
        #pragma unroll
        for (int j = 0; j < 4; ++j) {
            a0[j] = __hfma2(d0.h[j], w0, a0[j]);
            a1[j] = __hfma2(d1.h[j], w1, a1[j]);
            a2[j] = __hfma2(d2.h[j], w2, a2[j]);
        }
    }

    // sum planes -> A-frag (1/3 folded into W1F)
    union { __half2 h[4]; half8 v; } A;
    #pragma unroll
    for (int i = 0; i < 4; ++i)
        A.h[i] = __hadd2(__hadd2(a0[i], a1[i]), a2[i]);

    // layer 1: H[16 samples][64 hid] = X @ (W1/3) + b1 (bias in C-init)
    facc4 H[4];
    #pragma unroll
    for (int nt = 0; nt < 4; ++nt) {
        const float bb = b1[nt * 16 + c];          // C col = hid = nt*16+c
        facc4 Cb = {bb, bb, bb, bb};
        union { uint4 q; half8 v; } B;
        B.q = *(const uint4*)(W1F + (size_t)(nt * 64 + l) * 8);
        H[nt] = __builtin_amdgcn_mfma_f32_16x16x32_f16(A.v, B.v, Cb, 0, 0, 0);
    }

    // softplus -> f16 -> LDS (XOR swizzle: byte ^= (row&7)<<4)
    char* lb = (char*)&hlds[w][0];
    #pragma unroll
    for (int nt = 0; nt < 4; ++nt) {
        #pragma unroll
        for (int r = 0; r < 4; ++r) {
            const int row = g * 4 + r;                  // sample-in-wave
            const float hv = softplus_f(H[nt][r]);
            const int off = row * 128 + ((((nt * 16 + c) * 2)) ^ ((row & 7) << 4));
            *(u16*)(lb + off) = __half_as_ushort(__float2half_rn(hv));
        }
    }
    // wave-private LDS: compiler inserts lgkmcnt wait; no barrier needed.

    // layer 2: O[16][4] = softplus(H) @ W2 + b2 (bias in C-init; C col = c)
    const float bb2 = b2[c & 3];
    facc4 O = {bb2, bb2, bb2, bb2};
    #pragma unroll
    for (int kk = 0; kk < 2; ++kk) {
        union { uint4 q; half8 v; } A2;
        const int off = c * 128 + ((kk * 64 + g * 16) ^ ((c & 7) << 4));
        A2.q = *(const uint4*)(lb + off);
        union { uint4 q; half8 v; } B2;
        B2.q = *(const uint4*)(W2F + (size_t)(kk * 64 + l) * 8);
        O = __builtin_amdgcn_mfma_f32_16x16x32_f16(A2.v, B2.v, O, 0, 0, 0);
    }

    // epilogue: lane holds O[sample 4g+r][col c]; cols 0..3 valid -> LDS
    if (c < 4) {
        #pragma unroll
        for (int r = 0; r < 4; ++r) {
            const int li = w * 16 + g * 4 + r;
            const float o = O[r];
            const float val = (c == 0) ? softplus_f(o)
                                       : (sigmoid_f(o) * 1.002f - 0.001f);
            ((float*)&s_smp[li])[c] = val;
        }
    }
    if (g == 0) s_sd[ls] = sd;
    __syncthreads();

    // composite: wave 0 scans this block's ray (48 samples)
    if (w == 0) {
        const bool valid = l < NS;
        float4 v = make_float4(0.f, 0.f, 0.f, 0.f);
        float sdc = 0.f;
        if (valid) { v = s_smp[l]; sdc = s_sd[l]; }
        float sdn = __shfl_down(sdc, 1);

        float alpha = 0.f, lg = 0.f;
        if (valid) {
            float delta = (l < NS - 1) ? (sdn - sdc) : 1e10f;
            float tt = __expf(-delta * v.x);
            alpha = 1.0f - tt;
            lg = __logf(tt + 1e-10f);
        }
        float sacc = lg;
        #pragma unroll
        for (int off = 1; off < 64; off <<= 1) {
            float u = __shfl_up(sacc, off);
            if (l >= off) sacc += u;
        }
        float finalLog = __shfl(sacc, NS - 1);
        float T   = __expf(sacc - lg);
        float wgt = valid ? alpha * T : 0.f;

        float rf = wgt * v.y, gf = wgt * v.z, bf = wgt * v.w;
        float dep = wgt * sdc, wsum = wgt;
        #pragma unroll
        for (int off = 32; off; off >>= 1) {
            rf   += __shfl_xor(rf, off);
            gf   += __shfl_xor(gf, off);
            bf   += __shfl_xor(bf, off);
            dep  += __shfl_xor(dep, off);
            wsum += __shfl_xor(wsum, off);
        }
        if (l == 0) {
            out[ray * 3 + 0] = rf;
            out[ray * 3 + 1] = gf;
            out[ray * 3 + 2] = bf;
            out[NRAY * 3 + ray] = dep;
            out[NRAY * 4 + ray] = wsum;
            out[NRAY * 5 + ray] = __expf(finalLog);
        }
    }
}

// ---- fallback: fully fused fp32, direct plane layout -------------------
__global__ __launch_bounds__(192)
void render_fused(const float* __restrict__ pl,
                  const float* __restrict__ rayo,
                  const float* __restrict__ rayd,
                  const float* __restrict__ jitter,
                  const float* __restrict__ W1, const float* __restrict__ b1,
                  const float* __restrict__ W2, const float* __restrict__ b2,
                  float* __restrict__ out) {
    __shared__ float4 smpb[192];
    __shared__ float  sdsb[192];
    int tid = threadIdx.x;
    int lr  = tid / NS;
    int n   = tid - lr * NS;
    int ray = blockIdx.x * 4 + lr;
    int b   = ray >> 12;

    float jit = jitter[ray * NS + n];
    float sd  = (float)n * S_DELTA + jit * S_DELTA;
    float ox = rayo[ray*3+0], oy = rayo[ray*3+1], oz = rayo[ray*3+2];
    float dx = rayd[ray*3+0], dy = rayd[ray*3+1], dz = rayd[ray*3+2];
    float cx = fmaf(sd, dx, ox), cy = fmaf(sd, dy, oy), cz = fmaf(sd, dz, oz);

    float xv[32];
    #pragma unroll
    for (int i = 0; i < 32; ++i) xv[i] = 0.f;
    const size_t psz = (size_t)HP * HP * FEAT;
    const float* base = pl + (size_t)b * 3 * psz;
    float gxs[3] = {cx, cx, cy}, gys[3] = {cy, cz, cz};
    for (int p = 0; p < 3; ++p) {
        float px = (gxs[p] + 1.0f) * 0.5f * (float)(HP - 1);
        float py = (gys[p] + 1.0f) * 0.5f * (float)(HP - 1);
        float fx = floorf(px), fy = floorf(py);
        float wx = px - fx, wy = py - fy;
        int x0 = (int)fx, y0 = (int)fy, x1 = x0 + 1, y1 = y0 + 1;
        const float* pb = base + p * psz;
        float ws[4] = {(1.f-wx)*(1.f-wy), wx*(1.f-wy), (1.f-wx)*wy, wx*wy};
        int xs[4] = {x0, x1, x0, x1}, ys[4] = {y0, y0, y1, y1};
        for (int q = 0; q < 4; ++q) {
            if ((unsigned)xs[q] < HP && (unsigned)ys[q] < HP) {
                const float* pp = pb + (size_t)ys[q] * HP + xs[q];
                #pragma unroll
                for (int f = 0; f < 32; ++f)
                    xv[f] = fmaf(ws[q], pp[(size_t)f * HP * HP], xv[f]);
            }
        }
    }
    #pragma unroll
    for (int i = 0; i < 32; ++i) xv[i] *= (1.f/3.f);

    float o0 = b2[0], o1 = b2[1], o2 = b2[2], o3 = b2[3];
    #pragma unroll
    for (int j = 0; j < HID; ++j) {
        float hj = b1[j];
        #pragma unroll
        for (int f = 0; f < FEAT; ++f) hj = fmaf(xv[f], W1[f * HID + j], hj);
        hj = softplus_f(hj);
        o0 = fmaf(hj, W2[j*4+0], o0);
        o1 = fmaf(hj, W2[j*4+1], o1);
        o2 = fmaf(hj, W2[j*4+2], o2);
        o3 = fmaf(hj, W2[j*4+3], o3);
    }
    smpb[tid] = make_float4(softplus_f(o0),
                            sigmoid_f(o1) * 1.002f - 0.001f,
                            sigmoid_f(o2) * 1.002f - 0.001f,
                            sigmoid_f(o3) * 1.002f - 0.001f);
    sdsb[tid] = sd;
    __syncthreads();

    if (tid < 4) {
        int rray = blockIdx.x * 4 + tid;
        const float4* sp  = &smpb[tid * NS];
        const float*  sdp = &sdsb[tid * NS];
        float T = 1.0f, rf = 0.f, gf = 0.f, bfv = 0.f, dep = 0.f, wsum = 0.f;
        for (int m = 0; m < NS; ++m) {
            float4 vv = sp[m];
            float sdc = sdp[m];
            float delta = (m < NS - 1) ? (sdp[m+1] - sdc) : 1e10f;
            float alpha = 1.0f - __expf(-delta * vv.x);
            float wq = alpha * T;
            rf = fmaf(wq, vv.y, rf);
            gf = fmaf(wq, vv.z, gf);
            bfv = fmaf(wq, vv.w, bfv);
            dep = fmaf(wq, sdc, dep);
            wsum += wq;
            T *= (1.0f - alpha + 1e-10f);
        }
        out[rray*3+0] = rf;
        out[rray*3+1] = gf;
        out[rray*3+2] = bfv;
        out[NRAY*3 + rray] = dep;
        out[NRAY*4 + rray] = wsum;
        out[NRAY*5 + rray] = T;
    }
}

extern "C" void kernel_launch(void* const* d_in, const int* in_sizes, int n_in,
                              void* d_out, int out_size, void* d_ws, size_t ws_size,
                              hipStream_t stream) {
    const float* planes = (const float*)d_in[0];
    const float* rayo   = (const float*)d_in[1];
    const float* rayd   = (const float*)d_in[2];
    const float* jitter = (const float*)d_in[3];
    const float* W1     = (const float*)d_in[4];
    const float* b1     = (const float*)d_in[5];
    const float* W2     = (const float*)d_in[6];
    const float* b2     = (const float*)d_in[7];
    float* out = (float*)d_out;

    const size_t pT_bytes = (size_t)BATCH * 3 * HP * HP * FEAT * 2;  // 25.2 MB f16
    const size_t w1f_off  = pT_bytes;
    const size_t w2f_off  = w1f_off + (size_t)FEAT * HID * 2;  // 4 KB
    const size_t need     = w2f_off + (size_t)HID * 16 * 2;    // +2 KB

    if (ws_size >= need) {
        char* ws = (char*)d_ws;
        u16* pT  = (u16*)ws;
        u16* W1F = (u16*)(ws + w1f_off);
        u16* W2F = (u16*)(ws + w2f_off);
        const int tgrid = BATCH * 3 * HP * HP / 256 + 1;
        hipLaunchKernelGGL(prep_kernel, dim3(tgrid), dim3(256), 0, stream,
                           planes, W1, W2, pT, W1F, W2F);
        hipLaunchKernelGGL(render_mfma, dim3(NRAY), dim3(192), 0, stream,
                           pT, rayo, rayd, jitter, W1F, W2F, b1, b2, out);
    } else {
        hipLaunchKernelGGL(render_fused, dim3(NRAY / 4), dim3(192), 0, stream,
                           planes, rayo, rayd, jitter, W1, b1, W2, b2, out);
    }
}

// Round 17
// 57.917 us; speedup vs baseline: 1.2282x; 1.0089x over previous
//
#include <hip/hip_runtime.h>
#include <hip/hip_fp16.h>
#include <math.h>

#define BATCH 2
#define RAYS  4096
#define NS    48
#define FEAT  32
#define HP    256
#define HID   64
#define NRAY  (BATCH*RAYS)
#define NSAMP (NRAY*NS)
#define S_DELTA (1.0f/47.0f)
#define PSZ   (HP*HP*FEAT)          // elements per plane

typedef unsigned short u16;
typedef __attribute__((ext_vector_type(8))) _Float16 half8;  // 8 f16 (4 VGPRs)
typedef __attribute__((ext_vector_type(4))) float facc4;     // 4 f32 accum

__device__ __forceinline__ float softplus_f(float t) {
    float e = __expf(-fabsf(t));
    return fmaxf(t, 0.0f) + __logf(1.0f + e);
}
__device__ __forceinline__ float sigmoid_f(float t) {
    return 1.0f / (1.0f + __expf(-t));
}

// ---- prep: planes f32 [bp][f][y][x] -> f16 [bp][y][x][f]; W1/3,W2 -> f16 B-frags
__global__ __launch_bounds__(256)
void prep_kernel(const float* __restrict__ planes,
                 const float* __restrict__ W1,
                 const float* __restrict__ W2,
                 u16* __restrict__ pT,
                 u16* __restrict__ W1F,
                 u16* __restrict__ W2F) {
    int idx = blockIdx.x * 256 + threadIdx.x;
    const int total = BATCH * 3 * HP * HP;
    if (idx < total) {
        int xy = idx % (HP * HP);
        int bp = idx / (HP * HP);
        const float* src = planes + (size_t)bp * FEAT * HP * HP + xy;
        unsigned o16[16];
        #pragma unroll
        for (int k = 0; k < 16; ++k) {
            unsigned lo = __half_as_ushort(__float2half_rn(src[(size_t)(2*k)   * HP*HP]));
            unsigned hi = __half_as_ushort(__float2half_rn(src[(size_t)(2*k+1) * HP*HP]));
            o16[k] = lo | (hi << 16);
        }
        uint4* dst = (uint4*)(pT + (size_t)idx * FEAT);
        #pragma unroll
        for (int q = 0; q < 4; ++q)
            dst[q] = make_uint4(o16[4*q], o16[4*q+1], o16[4*q+2], o16[4*q+3]);
    } else {
        int r = idx - total;              // 0..255 (one tail block)
        // W1F: B-frag of (W1/3)[32 k][64 n]; e=(nt*64+l)*8+i holds
        // f16(W1[k=(l>>4)*8+i][n=nt*16+(l&15)] / 3)
        #pragma unroll
        for (int i = 0; i < 8; ++i) {
            int e = r * 8 + i;            // 0..2047
            int nt = e >> 9, ll = (e >> 3) & 63, ii = e & 7;
            int k = ((ll >> 4) << 3) + ii;
            int nn = (nt << 4) + (ll & 15);
            W1F[e] = __half_as_ushort(__float2half_rn(W1[k * HID + nn] * (1.f/3.f)));
        }
        // W2F: B-frag of W2 padded [64 k][16 n]
        if (r < 128) {
            #pragma unroll
            for (int i = 0; i < 8; ++i) {
                int e = r * 8 + i;        // 0..1023
                int kk = e >> 9, ll = (e >> 3) & 63, ii = e & 7;
                int k = kk * 32 + ((ll >> 4) << 3) + ii;
                int nn = ll & 15;
                W2F[e] = (nn < 4) ? __half_as_ushort(__float2half_rn(W2[k * 4 + nn]))
                                  : (u16)0;
            }
        }
    }
}

// ---- compute 4 corner offsets (u16 elements from pbase) + weights ------
__device__ __forceinline__ void plane_addr(float gx, float gy, int fc8, unsigned pofs,
                                           unsigned* __restrict__ offs,
                                           float* __restrict__ wts) {
    float px = fmaf(gx, 127.5f, 127.5f);   // (gx+1)*0.5*(HP-1)
    float py = fmaf(gy, 127.5f, 127.5f);
    float fx = floorf(px), fy = floorf(py);
    float wx = px - fx, wy = py - fy;
    int x0 = (int)fx, y0 = (int)fy;
    int x1 = x0 + 1, y1 = y0 + 1;
    bool vx0 = (unsigned)x0 < HP, vx1 = (unsigned)x1 < HP;
    bool vy0 = (unsigned)y0 < HP, vy1 = (unsigned)y1 < HP;
    int cx0 = min(max(x0, 0), HP-1), cx1 = min(max(x1, 0), HP-1);
    int cy0 = min(max(y0, 0), HP-1), cy1 = min(max(y1, 0), HP-1);
    unsigned a00 = (unsigned)(cy0 * HP + cx0) * FEAT + fc8 + pofs;
    unsigned dxe = (unsigned)(cx1 - cx0) * FEAT;        // 0 or 32
    unsigned dye = (unsigned)(cy1 - cy0) * (HP * FEAT); // 0 or 8192
    offs[0] = a00;
    offs[1] = a00 + dxe;
    offs[2] = a00 + dye;
    offs[3] = a00 + dye + dxe;
    wts[0] = (vx0 && vy0) ? (1.f-wx)*(1.f-wy) : 0.f;
    wts[1] = (vx1 && vy0) ? wx*(1.f-wy)       : 0.f;
    wts[2] = (vx0 && vy1) ? (1.f-wx)*wy       : 0.f;
    wts[3] = (vx1 && vy1) ? wx*wy             : 0.f;
}

// ---- fused: gather + f16 MFMA MLP + in-block composite -----------------
// block = 192 threads = 3 waves = 48 samples = EXACTLY ONE RAY.
// wave w: 16 samples; lane l: sample (l&15), feats (l>>4)*8..+7 == A-frag
// of mfma_f32_16x16x32_f16. C/D: row=4*(l>>4)+reg, col=l&15 (verified r7).
__global__ __launch_bounds__(192, 4)
void render_mfma(const u16* __restrict__ pT,
                 const float* __restrict__ rayo,
                 const float* __restrict__ rayd,
                 const float* __restrict__ jitter,
                 const u16* __restrict__ W1F,
                 const u16* __restrict__ W2F,
                 const float* __restrict__ b1,
                 const float* __restrict__ b2,
                 float* __restrict__ out) {
    __shared__ __align__(16) u16 hlds[3][1024];  // per-wave 16x64 f16, XOR-swizzled
    __shared__ __align__(16) float4 s_smp[48];   // {dens,r,g,b} per sample
    __shared__ float s_sd[48];

    const int t = threadIdx.x;
    const int w = t >> 6;
    const int l = t & 63;
    const int c = l & 15;          // A-row / C-col (sample-in-wave)
    const int g = l >> 4;          // k-chunk / C row-group
    const int ray = blockIdx.x;    // one ray per block
    const int ls = w * 16 + c;     // local sample == n
    const int s  = ray * NS + ls;  // global sample
    const int b  = ray >> 12;

    const float jit = jitter[s];
    const float sd = fmaf((float)ls, S_DELTA, jit * S_DELTA);
    const float ox = rayo[ray*3+0], oy = rayo[ray*3+1], oz = rayo[ray*3+2];
    const float dx = rayd[ray*3+0], dy = rayd[ray*3+1], dz = rayd[ray*3+2];
    const float cxv = fmaf(sd, dx, ox);
    const float cyv = fmaf(sd, dy, oy);
    const float czv = fmaf(sd, dz, oz);

    // phase A: all 12 corner offsets + weights
    const int fc8 = g * 8;
    unsigned offs[12];
    float wts[12];
    plane_addr(cxv, cyv, fc8, 0u,                offs + 0, wts + 0);  // (x,y)
    plane_addr(cxv, czv, fc8, (unsigned)PSZ,     offs + 4, wts + 4);  // (x,z)
    plane_addr(cyv, czv, fc8, (unsigned)(2*PSZ), offs + 8, wts + 8);  // (y,z)

    // phase B: 12 corner loads (uniform SGPR base + voffset)
    const u16* pbase = pT + (size_t)b * 3 * PSZ;   // wave-uniform
    uint4 dat[12];
    #pragma unroll
    for (int i = 0; i < 12; ++i)
        dat[i] = *(const uint4*)(pbase + offs[i]);

    // phase C: consume — 3 independent per-plane chains (ILP)
    __half2 a0[4], a1[4], a2[4];
    #pragma unroll
    for (int i = 0; i < 4; ++i) {
        a0[i] = __float2half2_rn(0.f);
        a1[i] = __float2half2_rn(0.f);
        a2[i] = __float2half2_rn(0.f);
    }
    #pragma unroll
    for (int q = 0; q < 4; ++q) {
        union { uint4 u; __half2 h[4]; } d0, d1, d2;
        d0.u = dat[q]; d1.u = dat[4+q]; d2.u = dat[8+q];
        __half2 w0 = __float2half2_rn(wts[q]);
        __half2 w1 = __float2half2_rn(wts[4+q]);
        __half2 w2 = __float2half2_rn(wts[8+q]);
        #pragma unroll
        for (int j = 0; j < 4; ++j) {
            a0[j] = __hfma2(d0.h[j], w0, a0[j]);
            a1[j] = __hfma2(d1.h[j], w1, a1[j]);
            a2[j] = __hfma2(d2.h[j], w2, a2[j]);
        }
    }

    // sum planes -> A-frag (1/3 folded into W1F)
    union { __half2 h[4]; half8 v; } A;
    #pragma unroll
    for (int i = 0; i < 4; ++i)
        A.h[i] = __hadd2(__hadd2(a0[i], a1[i]), a2[i]);

    // layer 1: H[16 samples][64 hid] = X @ (W1/3) + b1 (bias in C-init)
    facc4 H[4];
    #pragma unroll
    for (int nt = 0; nt < 4; ++nt) {
        const float bb = b1[nt * 16 + c];          // C col = hid = nt*16+c
        facc4 Cb = {bb, bb, bb, bb};
        union { uint4 q; half8 v; } B;
        B.q = *(const uint4*)(W1F + (size_t)(nt * 64 + l) * 8);
        H[nt] = __builtin_amdgcn_mfma_f32_16x16x32_f16(A.v, B.v, Cb, 0, 0, 0);
    }

    // softplus -> f16 -> LDS (XOR swizzle: byte ^= (row&7)<<4)
    char* lb = (char*)&hlds[w][0];
    #pragma unroll
    for (int nt = 0; nt < 4; ++nt) {
        #pragma unroll
        for (int r = 0; r < 4; ++r) {
            const int row = g * 4 + r;                  // sample-in-wave
            const float hv = softplus_f(H[nt][r]);
            const int off = row * 128 + ((((nt * 16 + c) * 2)) ^ ((row & 7) << 4));
            *(u16*)(lb + off) = __half_as_ushort(__float2half_rn(hv));
        }
    }
    // wave-private LDS: compiler inserts lgkmcnt wait; no barrier needed.

    // layer 2: O[16][4] = softplus(H) @ W2 + b2 (bias in C-init; C col = c)
    const float bb2 = b2[c & 3];
    facc4 O = {bb2, bb2, bb2, bb2};
    #pragma unroll
    for (int kk = 0; kk < 2; ++kk) {
        union { uint4 q; half8 v; } A2;
        const int off = c * 128 + ((kk * 64 + g * 16) ^ ((c & 7) << 4));
        A2.q = *(const uint4*)(lb + off);
        union { uint4 q; half8 v; } B2;
        B2.q = *(const uint4*)(W2F + (size_t)(kk * 64 + l) * 8);
        O = __builtin_amdgcn_mfma_f32_16x16x32_f16(A2.v, B2.v, O, 0, 0, 0);
    }

    // epilogue: lane holds O[sample 4g+r][col c]; cols 0..3 valid -> LDS
    if (c < 4) {
        #pragma unroll
        for (int r = 0; r < 4; ++r) {
            const int li = w * 16 + g * 4 + r;
            const float o = O[r];
            const float val = (c == 0) ? softplus_f(o)
                                       : (sigmoid_f(o) * 1.002f - 0.001f);
            ((float*)&s_smp[li])[c] = val;
        }
    }
    if (g == 0) s_sd[ls] = sd;
    __syncthreads();

    // composite: wave 0 scans this block's ray (48 samples)
    if (w == 0) {
        const bool valid = l < NS;
        float4 v = make_float4(0.f, 0.f, 0.f, 0.f);
        float sdc = 0.f;
        if (valid) { v = s_smp[l]; sdc = s_sd[l]; }
        float sdn = __shfl_down(sdc, 1);

        float alpha = 0.f, lg = 0.f;
        if (valid) {
            float delta = (l < NS - 1) ? (sdn - sdc) : 1e10f;
            float x = delta * v.x;                 // >= 0 (dens = softplus > 0)
            alpha = 1.0f - __expf(-x);
            // log(exp(-x) + 1e-10) == max(-x, ln 1e-10) to within 1e-10 abs in T
            lg = fmaxf(-x, -23.0258509f);
        }
        float sacc = lg;
        #pragma unroll
        for (int off = 1; off < 64; off <<= 1) {
            float u = __shfl_up(sacc, off);
            if (l >= off) sacc += u;
        }
        float finalLog = __shfl(sacc, NS - 1);
        float T   = __expf(sacc - lg);
        float wgt = valid ? alpha * T : 0.f;

        float rf = wgt * v.y, gf = wgt * v.z, bf = wgt * v.w;
        float dep = wgt * sdc, wsum = wgt;
        #pragma unroll
        for (int off = 32; off; off >>= 1) {
            rf   += __shfl_xor(rf, off);
            gf   += __shfl_xor(gf, off);
            bf   += __shfl_xor(bf, off);
            dep  += __shfl_xor(dep, off);
            wsum += __shfl_xor(wsum, off);
        }
        if (l == 0) {
            out[ray * 3 + 0] = rf;
            out[ray * 3 + 1] = gf;
            out[ray * 3 + 2] = bf;
            out[NRAY * 3 + ray] = dep;
            out[NRAY * 4 + ray] = wsum;
            out[NRAY * 5 + ray] = __expf(finalLog);
        }
    }
}

// ---- fallback: fully fused fp32, direct plane layout -------------------
__global__ __launch_bounds__(192)
void render_fused(const float* __restrict__ pl,
                  const float* __restrict__ rayo,
                  const float* __restrict__ rayd,
                  const float* __restrict__ jitter,
                  const float* __restrict__ W1, const float* __restrict__ b1,
                  const float* __restrict__ W2, const float* __restrict__ b2,
                  float* __restrict__ out) {
    __shared__ float4 smpb[192];
    __shared__ float  sdsb[192];
    int tid = threadIdx.x;
    int lr  = tid / NS;
    int n   = tid - lr * NS;
    int ray = blockIdx.x * 4 + lr;
    int b   = ray >> 12;

    float jit = jitter[ray * NS + n];
    float sd  = (float)n * S_DELTA + jit * S_DELTA;
    float ox = rayo[ray*3+0], oy = rayo[ray*3+1], oz = rayo[ray*3+2];
    float dx = rayd[ray*3+0], dy = rayd[ray*3+1], dz = rayd[ray*3+2];
    float cx = fmaf(sd, dx, ox), cy = fmaf(sd, dy, oy), cz = fmaf(sd, dz, oz);

    float xv[32];
    #pragma unroll
    for (int i = 0; i < 32; ++i) xv[i] = 0.f;
    const size_t psz = (size_t)HP * HP * FEAT;
    const float* base = pl + (size_t)b * 3 * psz;
    float gxs[3] = {cx, cx, cy}, gys[3] = {cy, cz, cz};
    for (int p = 0; p < 3; ++p) {
        float px = (gxs[p] + 1.0f) * 0.5f * (float)(HP - 1);
        float py = (gys[p] + 1.0f) * 0.5f * (float)(HP - 1);
        float fx = floorf(px), fy = floorf(py);
        float wx = px - fx, wy = py - fy;
        int x0 = (int)fx, y0 = (int)fy, x1 = x0 + 1, y1 = y0 + 1;
        const float* pb = base + p * psz;
        float ws[4] = {(1.f-wx)*(1.f-wy), wx*(1.f-wy), (1.f-wx)*wy, wx*wy};
        int xs[4] = {x0, x1, x0, x1}, ys[4] = {y0, y0, y1, y1};
        for (int q = 0; q < 4; ++q) {
            if ((unsigned)xs[q] < HP && (unsigned)ys[q] < HP) {
                const float* pp = pb + (size_t)ys[q] * HP + xs[q];
                #pragma unroll
                for (int f = 0; f < 32; ++f)
                    xv[f] = fmaf(ws[q], pp[(size_t)f * HP * HP], xv[f]);
            }
        }
    }
    #pragma unroll
    for (int i = 0; i < 32; ++i) xv[i] *= (1.f/3.f);

    float o0 = b2[0], o1 = b2[1], o2 = b2[2], o3 = b2[3];
    #pragma unroll
    for (int j = 0; j < HID; ++j) {
        float hj = b1[j];
        #pragma unroll
        for (int f = 0; f < FEAT; ++f) hj = fmaf(xv[f], W1[f * HID + j], hj);
        hj = softplus_f(hj);
        o0 = fmaf(hj, W2[j*4+0], o0);
        o1 = fmaf(hj, W2[j*4+1], o1);
        o2 = fmaf(hj, W2[j*4+2], o2);
        o3 = fmaf(hj, W2[j*4+3], o3);
    }
    smpb[tid] = make_float4(softplus_f(o0),
                            sigmoid_f(o1) * 1.002f - 0.001f,
                            sigmoid_f(o2) * 1.002f - 0.001f,
                            sigmoid_f(o3) * 1.002f - 0.001f);
    sdsb[tid] = sd;
    __syncthreads();

    if (tid < 4) {
        int rray = blockIdx.x * 4 + tid;
        const float4* sp  = &smpb[tid * NS];
        const float*  sdp = &sdsb[tid * NS];
        float T = 1.0f, rf = 0.f, gf = 0.f, bfv = 0.f, dep = 0.f, wsum = 0.f;
        for (int m = 0; m < NS; ++m) {
            float4 vv = sp[m];
            float sdc = sdp[m];
            float delta = (m < NS - 1) ? (sdp[m+1] - sdc) : 1e10f;
            float alpha = 1.0f - __expf(-delta * vv.x);
            float wq = alpha * T;
            rf = fmaf(wq, vv.y, rf);
            gf = fmaf(wq, vv.z, gf);
            bfv = fmaf(wq, vv.w, bfv);
            dep = fmaf(wq, sdc, dep);
            wsum += wq;
            T *= (1.0f - alpha + 1e-10f);
        }
        out[rray*3+0] = rf;
        out[rray*3+1] = gf;
        out[rray*3+2] = bfv;
        out[NRAY*3 + rray] = dep;
        out[NRAY*4 + rray] = wsum;
        out[NRAY*5 + rray] = T;
    }
}

extern "C" void kernel_launch(void* const* d_in, const int* in_sizes, int n_in,
                              void* d_out, int out_size, void* d_ws, size_t ws_size,
                              hipStream_t stream) {
    const float* planes = (const float*)d_in[0];
    const float* rayo   = (const float*)d_in[1];
    const float* rayd   = (const float*)d_in[2];
    const float* jitter = (const float*)d_in[3];
    const float* W1     = (const float*)d_in[4];
    const float* b1     = (const float*)d_in[5];
    const float* W2     = (const float*)d_in[6];
    const float* b2     = (const float*)d_in[7];
    float* out = (float*)d_out;

    const size_t pT_bytes = (size_t)BATCH * 3 * HP * HP * FEAT * 2;  // 25.2 MB f16
    const size_t w1f_off  = pT_bytes;
    const size_t w2f_off  = w1f_off + (size_t)FEAT * HID * 2;  // 4 KB
    const size_t need     = w2f_off + (size_t)HID * 16 * 2;    // +2 KB

    if (ws_size >= need) {
        char* ws = (char*)d_ws;
        u16* pT  = (u16*)ws;
        u16* W1F = (u16*)(ws + w1f_off);
        u16* W2F = (u16*)(ws + w2f_off);
        const int tgrid = BATCH * 3 * HP * HP / 256 + 1;
        hipLaunchKernelGGL(prep_kernel, dim3(tgrid), dim3(256), 0, stream,
                           planes, W1, W2, pT, W1F, W2F);
        hipLaunchKernelGGL(render_mfma, dim3(NRAY), dim3(192), 0, stream,
                           pT, rayo, rayd, jitter, W1F, W2F, b1, b2, out);
    } else {
        hipLaunchKernelGGL(render_fused, dim3(NRAY / 4), dim3(192), 0, stream,
                           planes, rayo, rayd, jitter, W1, b1, W2, b2, out);
    }
}